// Round 11
// baseline (333.308 us; speedup 1.0000x reference)
//
#include <hip/hip_runtime.h>

#define NN 100000
#define NB 196            // ceil(NN / 512) buckets of 512 nodes
#define CH 4096           // edges per block in k_bscatter3

typedef short short8 __attribute__((ext_vector_type(8)));
typedef unsigned short u16x8 __attribute__((ext_vector_type(8)));
typedef float f32x4 __attribute__((ext_vector_type(4)));

__device__ inline unsigned short f2bf(float x) {
    unsigned u = __float_as_uint(x);
    unsigned r = (u + 0x7FFF + ((u >> 16) & 1)) >> 16;
    return (unsigned short)r;
}
__device__ inline float bf2f(unsigned short h) {
    return __uint_as_float(((unsigned)h) << 16);
}

// ---------------- bucket histograms (src & dst) via LDS ----------------
__global__ __launch_bounds__(256) void k_bhist2(const int* __restrict__ src,
    const int* __restrict__ dst, int* __restrict__ bcntS, int* __restrict__ bcntD, int E)
{
    __shared__ int hs[NB], hd[NB];
    int t = threadIdx.x;
    if (t < NB) { hs[t] = 0; hd[t] = 0; }
    __syncthreads();
    int stride = gridDim.x * 256;
    for (int e = blockIdx.x * 256 + t; e < E; e += stride) {
        atomicAdd(&hs[src[e] >> 9], 1);
        atomicAdd(&hd[dst[e] >> 9], 1);
    }
    __syncthreads();
    if (t < NB) {
        if (hs[t]) atomicAdd(&bcntS[t], hs[t]);
        if (hd[t]) atomicAdd(&bcntD[t], hd[t]);
    }
}

// ---------------- exact bucket scans (dense tmp layout) ----------------
__global__ __launch_bounds__(256) void k_bscan2(const int* __restrict__ bcntS,
    const int* __restrict__ bcntD, int* __restrict__ bbaseS, int* __restrict__ gcurS,
    int* __restrict__ bbaseD, int* __restrict__ gcurD)
{
    __shared__ int s[256];
    int t = threadIdx.x;
    int cD = (t < NB) ? bcntD[t] : 0;
    int cS = (t < NB) ? bcntS[t] : 0;

    int v = cD;
    s[t] = v;
    __syncthreads();
#pragma unroll
    for (int off = 1; off < 256; off <<= 1) {
        int x = (t >= off) ? s[t - off] : 0;
        __syncthreads(); s[t] += x; __syncthreads();
    }
    if (t < NB) { int e = s[t] - v; bbaseD[t] = e; gcurD[t] = e; }
    __syncthreads();

    v = cS;
    s[t] = v;
    __syncthreads();
#pragma unroll
    for (int off = 1; off < 256; off <<= 1) {
        int x = (t >= off) ? s[t - off] : 0;
        __syncthreads(); s[t] += x; __syncthreads();
    }
    if (t < NB) { int e = s[t] - v; bbaseS[t] = e; gcurS[t] = e; }
}

// ---------------- one-shot counting-claim bucket scatter ----------------
__global__ __launch_bounds__(256) void k_bscatter3(const int* __restrict__ src,
    const int* __restrict__ dst, int* __restrict__ gcurD, int* __restrict__ gcurS,
    unsigned* __restrict__ tmpD, unsigned* __restrict__ tmpS, int E)
{
    __shared__ int cntD[NB], cntS[NB];
    __shared__ int runD[NB], runS[NB];
    int t = threadIdx.x;
    if (t < NB) { cntD[t] = 0; cntS[t] = 0; }
    __syncthreads();

    const int e0 = blockIdx.x * CH;
    int sv[16], dv[16];
    int offD[16], offS[16];
#pragma unroll
    for (int i = 0; i < 16; i++) {
        int e = e0 + i * 256 + t;
        if (e < E) { sv[i] = src[e]; dv[i] = dst[e]; }
    }
#pragma unroll
    for (int i = 0; i < 16; i++) {
        int e = e0 + i * 256 + t;
        if (e < E) {
            offD[i] = atomicAdd(&cntD[dv[i] >> 9], 1);
            offS[i] = atomicAdd(&cntS[sv[i] >> 9], 1);
        }
    }
    __syncthreads();
    if (t < NB) {
        int c = cntD[t];
        if (c) runD[t] = atomicAdd(&gcurD[t], c);
        c = cntS[t];
        if (c) runS[t] = atomicAdd(&gcurS[t], c);
    }
    __syncthreads();
#pragma unroll
    for (int i = 0; i < 16; i++) {
        int e = e0 + i * 256 + t;
        if (e < E) {
            int bD = dv[i] >> 9;
            tmpD[runD[bD] + offD[i]] = (unsigned)sv[i] | ((unsigned)(dv[i] & 511) << 17);
            int bS = sv[i] >> 9;
            tmpS[runS[bS] + offS[i]] = (unsigned)(sv[i] & 511);
        }
    }
}

// ---------------- src-bucket count -> ns ----------------
__global__ __launch_bounds__(256) void k_cntS(const int* __restrict__ bbaseS,
    const int* __restrict__ bcntS, const unsigned* __restrict__ tmpS,
    float* __restrict__ ns, int N)
{
    __shared__ int cnt[512];
    int b = blockIdx.x, t = threadIdx.x;
    cnt[t] = 0; cnt[t + 256] = 0;
    __syncthreads();
    int beg = bbaseS[b], end = beg + bcntS[b];
    for (int e = beg + t; e < end; e += 256)
        atomicAdd(&cnt[tmpS[e]], 1);
    __syncthreads();
    int nb = b << 9;
    for (int i = t; i < 512; i += 256) {
        int n = nb + i;
        if (n < N) ns[n] = rsqrtf(fmaxf((float)cnt[i], 1.0f));
    }
}

// ---------------- dst-bucket: degI + nd + rowptr + src-ordered CSR fill ----------------
__global__ __launch_bounds__(256) void k_csrD(const int* __restrict__ bbaseD,
    const int* __restrict__ bcntD, const unsigned* __restrict__ tmpD,
    int* __restrict__ degI, float* __restrict__ nd,
    int* __restrict__ rowptr, int* __restrict__ srcIdx, int N)
{
    __shared__ int cnt[8192];      // [dlocal][16 src-parts], 32 KB
    __shared__ int sblk[256];
    int b = blockIdx.x, t = threadIdx.x;
    for (int i = t; i < 8192; i += 256) cnt[i] = 0;
    __syncthreads();
    int beg = bbaseD[b], end = beg + bcntD[b];
    for (int e = beg + t; e < end; e += 256) {
        unsigned v = tmpD[e];
        int dl = v >> 17;
        int s  = (int)(v & 0x1FFFFu);
        atomicAdd(&cnt[(dl << 4) | (s >> 13)], 1);
    }
    __syncthreads();
    int loc[32];
    int sum = 0;
#pragma unroll
    for (int i = 0; i < 32; i++) { loc[i] = sum; sum += cnt[t * 32 + i]; }
    sblk[t] = sum;
    __syncthreads();
#pragma unroll
    for (int off = 1; off < 256; off <<= 1) {
        int x = (t >= off) ? sblk[t - off] : 0;
        __syncthreads(); sblk[t] += x; __syncthreads();
    }
    int base = beg + sblk[t] - sum;
    int v0 = loc[16];
    int v1 = sum - loc[16];
    int nb = b << 9;
    int n0 = nb + 2 * t, n1 = n0 + 1;
    if (n0 < N) { rowptr[n0] = base;           degI[n0] = v0; nd[n0] = rsqrtf(fmaxf((float)v0, 1.f)); }
    if (n1 < N) { rowptr[n1] = base + loc[16]; degI[n1] = v1; nd[n1] = rsqrtf(fmaxf((float)v1, 1.f)); }
#pragma unroll
    for (int i = 0; i < 32; i++) cnt[t * 32 + i] = base + loc[i];
    __syncthreads();
    for (int e = beg + t; e < end; e += 256) {
        unsigned v = tmpD[e];
        int dl = v >> 17;
        int s  = (int)(v & 0x1FFFFu);
        int pos = atomicAdd(&cnt[(dl << 4) | (s >> 13)], 1);
        srcIdx[pos] = s;
    }
}

// ---------------- W prep: transpose + bf16 split + XOR-swizzle ----------------
template<int DOUT>
__global__ __launch_bounds__(256) void k_prepW(const float* __restrict__ W,
    unsigned short* __restrict__ Wh, unsigned short* __restrict__ Wl)
{
    int idx = blockIdx.x * 256 + threadIdx.x;
    if (idx >= 128 * DOUT) return;
    int c = idx % DOUT;
    int k = idx / DOUT;
    float w = W[idx];
    unsigned short hi = f2bf(w);
    unsigned short lo = f2bf(w - bf2f(hi));
    int boff = c * 256 + ((2 * k) ^ ((c & 7) << 4));
    *(unsigned short*)((char*)Wh + boff) = hi;
    *(unsigned short*)((char*)Wl + boff) = lo;
}

// ---------------- MFMA GEMM layer 1: out[n][:] = (x[n][:]*ns[n]) @ W ----------------
template<int DOUT>
__global__ __launch_bounds__(256) void k_gemm_mfma(
    const float* __restrict__ in,
    const unsigned short* __restrict__ Wth, const unsigned short* __restrict__ Wtl,
    const float* __restrict__ ns,
    unsigned short* __restrict__ out, int N)
{
    constexpr int NT = DOUT / 16;
    __shared__ __align__(16) unsigned short Wh[DOUT * 128];
    __shared__ __align__(16) unsigned short Wl[DOUT * 128];

    const int t = threadIdx.x;
    const int w = t >> 6, l = t & 63;

#pragma unroll
    for (int i = 0; i < DOUT * 256 / 4096; i++) {
        int off = i * 4096 + t * 16;
        *(float4*)((char*)Wh + off) = *(const float4*)((const char*)Wth + off);
        *(float4*)((char*)Wl + off) = *(const float4*)((const char*)Wtl + off);
    }

    const int rl   = l & 15;
    const int kgrp = l >> 4;
    const int row  = blockIdx.x * 64 + w * 16 + rl;
    const int rowc = row < N ? row : N - 1;
    const float* arow = in + (size_t)rowc * 128;

    float av[4][8];
#pragma unroll
    for (int ks = 0; ks < 4; ks++) {
        int kb = ks * 32 + kgrp * 8;
        float4 v0 = *(const float4*)(arow + kb);
        float4 v1 = *(const float4*)(arow + kb + 4);
        av[ks][0] = v0.x; av[ks][1] = v0.y; av[ks][2] = v0.z; av[ks][3] = v0.w;
        av[ks][4] = v1.x; av[ks][5] = v1.y; av[ks][6] = v1.z; av[ks][7] = v1.w;
    }
    float nsv = ns[rowc];
    short8 Ah[4], Al[4];
#pragma unroll
    for (int ks = 0; ks < 4; ks++)
#pragma unroll
        for (int j = 0; j < 8; j++) {
            float v = av[ks][j] * nsv;
            unsigned short hi = f2bf(v);
            Ah[ks][j] = (short)hi;
            Al[ks][j] = (short)f2bf(v - bf2f(hi));
        }

    __syncthreads();

    f32x4 acc[NT];
#pragma unroll
    for (int tt = 0; tt < NT; tt++) acc[tt] = (f32x4){0.f, 0.f, 0.f, 0.f};

#pragma unroll
    for (int ks = 0; ks < 4; ks++) {
        int kbyte = ks * 64 + kgrp * 16;
#pragma unroll
        for (int tt = 0; tt < NT; tt++) {
            int c = tt * 16 + rl;
            int boff = c * 256 + (kbyte ^ ((c & 7) << 4));
            short8 Bh = *(short8*)((char*)Wh + boff);
            short8 Bl = *(short8*)((char*)Wl + boff);
            acc[tt] = __builtin_amdgcn_mfma_f32_16x16x32_bf16(Ah[ks], Bh, acc[tt], 0, 0, 0);
            acc[tt] = __builtin_amdgcn_mfma_f32_16x16x32_bf16(Al[ks], Bh, acc[tt], 0, 0, 0);
            acc[tt] = __builtin_amdgcn_mfma_f32_16x16x32_bf16(Ah[ks], Bl, acc[tt], 0, 0, 0);
        }
    }

    const int orow = blockIdx.x * 64 + w * 16 + kgrp * 4;
#pragma unroll
    for (int r = 0; r < 4; r++) {
        if (orow + r < N) {
#pragma unroll
            for (int tt = 0; tt < NT; tt++)
                out[(size_t)(orow + r) * DOUT + tt * 16 + rl] = f2bf(acc[tt][r]);
        }
    }
}

// ---------------- FUSED gather-GEMM v2: coalesced k_agg-style gather + LDS handoff ----------------
// gather: 4 generations x (4 nodes x 16 lanes x u16x8), 256B coalesced, max-of-4 divergence
// handoff: fx[64][132] f32 (LDS, padded), re-read in MFMA (rl,kgrp) layout
// W staged in the SAME LDS (aliased) in 64-column phases after fx is consumed
template<int DOUT>
__global__ __launch_bounds__(256, 4) void k_gemm_gather(
    const int* __restrict__ rowptr, const int* __restrict__ degI,
    const int* __restrict__ srcIdx, const unsigned short* __restrict__ h,
    const unsigned short* __restrict__ Wth, const unsigned short* __restrict__ Wtl,
    const float* __restrict__ bprev,
    const float* __restrict__ ns, const float* __restrict__ nd,
    unsigned short* __restrict__ out, int N)
{
    constexpr int NT = DOUT / 16;
    constexpr int PH = DOUT / 64;              // 2 (DOUT=128) or 1 (DOUT=64)
    __shared__ __align__(16) float fx[64][132];             // 33792 B, reused for W
    unsigned short* Wh = (unsigned short*)&fx[0][0];        // 16 KB
    unsigned short* Wl = Wh + 64 * 128;                     // 16 KB

    const int t = threadIdx.x;
    const int w = t >> 6, l = t & 63;
    const int lane16 = l & 15;        // channel group: 8 ch at lane16*8
    const int sub    = l >> 4;        // node within generation

    // ---- gather phase: coalesced, 2-deep unrolled ----
#pragma unroll
    for (int g = 0; g < 4; g++) {
        int row = blockIdx.x * 64 + w * 16 + g * 4 + sub;
        float a8[8] = {0.f, 0.f, 0.f, 0.f, 0.f, 0.f, 0.f, 0.f};
        if (row < N) {
            int beg = rowptr[row];
            int end = beg + degI[row];
            const unsigned short* hc = h + lane16 * 8;
            int e = beg;
            for (; e + 1 < end; e += 2) {
                int s0 = srcIdx[e], s1 = srcIdx[e + 1];
                u16x8 v0 = *(const u16x8*)(hc + (size_t)s0 * 128);
                u16x8 v1 = *(const u16x8*)(hc + (size_t)s1 * 128);
#pragma unroll
                for (int j = 0; j < 8; j++) a8[j] += bf2f(v0[j]) + bf2f(v1[j]);
            }
            if (e < end) {
                int s0 = srcIdx[e];
                u16x8 v0 = *(const u16x8*)(hc + (size_t)s0 * 128);
#pragma unroll
                for (int j = 0; j < 8; j++) a8[j] += bf2f(v0[j]);
            }
        }
        float* dp = &fx[w * 16 + g * 4 + sub][lane16 * 8];
#pragma unroll
        for (int j = 0; j < 8; j++) dp[j] = a8[j];
    }
    __syncthreads();

    // ---- epilogue in MFMA layout + bf16 split ----
    const int rl   = l & 15;
    const int kgrp = l >> 4;
    const int row  = blockIdx.x * 64 + w * 16 + rl;
    short8 Ah[4], Al[4];
    {
        float ndv = 0.f, nsv = 0.f;
        if (row < N) { ndv = nd[row]; nsv = ns[row]; }
#pragma unroll
        for (int ks = 0; ks < 4; ks++) {
            int kb = ks * 32 + kgrp * 8;
            const float* fr = &fx[w * 16 + rl][kb];
#pragma unroll
            for (int j = 0; j < 8; j++) {
                float v = fmaxf(fr[j] * ndv + bprev[kb + j], 0.f) * nsv;
                unsigned short hi = f2bf(v);
                Ah[ks][j] = (short)hi;
                Al[ks][j] = (short)f2bf(v - bf2f(hi));
            }
        }
    }
    __syncthreads();   // fx reads complete before W overwrites the same LDS

    // ---- phased MFMA: stage 64 W columns at a time into aliased LDS ----
    f32x4 acc[NT];
#pragma unroll
    for (int tt = 0; tt < NT; tt++) acc[tt] = (f32x4){0.f, 0.f, 0.f, 0.f};

#pragma unroll
    for (int ph = 0; ph < PH; ph++) {
#pragma unroll
        for (int i = 0; i < 4; i++) {
            int off = (i * 256 + t) * 16;   // 16 KB per buffer
            *(float4*)((char*)Wh + off) = *(const float4*)((const char*)Wth + ph * 16384 + off);
            *(float4*)((char*)Wl + off) = *(const float4*)((const char*)Wtl + ph * 16384 + off);
        }
        __syncthreads();
#pragma unroll
        for (int ks = 0; ks < 4; ks++) {
            int kbyte = ks * 64 + kgrp * 16;
#pragma unroll
            for (int tt = 0; tt < 4; tt++) {
                int c = tt * 16 + rl;       // column within phase
                int boff = c * 256 + (kbyte ^ ((c & 7) << 4));
                short8 Bh = *(short8*)((char*)Wh + boff);
                short8 Bl = *(short8*)((char*)Wl + boff);
                acc[ph * 4 + tt] = __builtin_amdgcn_mfma_f32_16x16x32_bf16(Ah[ks], Bh, acc[ph * 4 + tt], 0, 0, 0);
                acc[ph * 4 + tt] = __builtin_amdgcn_mfma_f32_16x16x32_bf16(Al[ks], Bh, acc[ph * 4 + tt], 0, 0, 0);
                acc[ph * 4 + tt] = __builtin_amdgcn_mfma_f32_16x16x32_bf16(Ah[ks], Bl, acc[ph * 4 + tt], 0, 0, 0);
            }
        }
        if (ph + 1 < PH) __syncthreads();   // reads done before next phase's stores
    }

    // ---- store: global col = tt*16 + rl (tt = ph*4 + tt_local) ----
    const int orow = blockIdx.x * 64 + w * 16 + kgrp * 4;
#pragma unroll
    for (int r = 0; r < 4; r++) {
        if (orow + r < N) {
#pragma unroll
            for (int tt = 0; tt < NT; tt++)
                out[(size_t)(orow + r) * DOUT + tt * 16 + rl] = f2bf(acc[tt][r]);
        }
    }
}

// ---------------- final aggregation (bf16 gather, f32 accumulate, epilogue) ----------------
template<int D>
__global__ __launch_bounds__(256) void k_agg_final(
    const int* __restrict__ rowptr, const int* __restrict__ cnt,
    const int* __restrict__ srcIdx, const unsigned short* __restrict__ h,
    const float* __restrict__ nd, const float* __restrict__ b3,
    float* __restrict__ m, int N)
{
    constexpr int TPN = D / 8;
    constexpr int NPB = 256 / TPN;
    int t = threadIdx.x;
    int node = blockIdx.x * NPB + t / TPN;
    if (node >= N) return;
    int c = (t % TPN) * 8;

    int beg = rowptr[node];
    int end = beg + cnt[node];
    float acc[8] = {0.f, 0.f, 0.f, 0.f, 0.f, 0.f, 0.f, 0.f};
    int e = beg;
    for (; e + 1 < end; e += 2) {
        int s0 = srcIdx[e], s1 = srcIdx[e + 1];
        u16x8 v0 = *(const u16x8*)&h[(size_t)s0 * D + c];
        u16x8 v1 = *(const u16x8*)&h[(size_t)s1 * D + c];
#pragma unroll
        for (int j = 0; j < 8; j++) acc[j] += bf2f(v0[j]) + bf2f(v1[j]);
    }
    if (e < end) {
        int s0 = srcIdx[e];
        u16x8 v0 = *(const u16x8*)&h[(size_t)s0 * D + c];
#pragma unroll
        for (int j = 0; j < 8; j++) acc[j] += bf2f(v0[j]);
    }
    float ndv = nd[node];
#pragma unroll
    for (int j = 0; j < 8; j++) acc[j] = acc[j] * ndv + b3[c + j];
    float4* mp = (float4*)&m[(size_t)node * D + c];
    mp[0] = make_float4(acc[0], acc[1], acc[2], acc[3]);
    mp[1] = make_float4(acc[4], acc[5], acc[6], acc[7]);
}

extern "C" void kernel_launch(void* const* d_in, const int* in_sizes, int n_in,
                              void* d_out, int out_size, void* d_ws, size_t ws_size,
                              hipStream_t stream) {
    const float* x  = (const float*)d_in[0];
    const int*   src = (const int*)d_in[1];
    const int*   dst = (const int*)d_in[2];
    const float* W1 = (const float*)d_in[3];
    const float* b1 = (const float*)d_in[4];
    const float* W2 = (const float*)d_in[5];
    const float* b2 = (const float*)d_in[6];
    const float* W3 = (const float*)d_in[7];
    const float* b3 = (const float*)d_in[8];
    float* out = (float*)d_out;

    const int N = NN;
    const int E = in_sizes[1];

    char* ws = (char*)d_ws;
    unsigned short* bufA = (unsigned short*)ws;                 // h1 / h3 bf16 (aliases tmpD)
    unsigned short* bufB = (unsigned short*)(ws + (size_t)N * 128 * 4); // h2 bf16 (aliases tmpS)
    unsigned* tmpD = (unsigned*)bufA;                           // consumed by k_csrD before gemm1 writes bufA
    unsigned* tmpS = (unsigned*)bufB;                           // consumed by k_cntS before gemm2F writes bufB
    char*  p     = ws + (size_t)N * 128 * 4 * 2;
    float* ns    = (float*)p;              p += (size_t)N * 4;
    float* nd    = (float*)p;              p += (size_t)N * 4;
    int*   degI  = (int*)p;                p += (size_t)N * 4;
    int*   rowp  = (int*)p;                p += (size_t)N * 4;
    int*   srcIdx= (int*)p;                p += (size_t)E * 4;
    unsigned short* W1h = (unsigned short*)p; p += 128 * 128 * 2;
    unsigned short* W1l = (unsigned short*)p; p += 128 * 128 * 2;
    unsigned short* W2h = (unsigned short*)p; p += 128 * 128 * 2;
    unsigned short* W2l = (unsigned short*)p; p += 128 * 128 * 2;
    unsigned short* W3h = (unsigned short*)p; p += 64 * 128 * 2;
    unsigned short* W3l = (unsigned short*)p; p += 64 * 128 * 2;
    int* bcntS = (int*)p;                  p += 256 * 4;
    int* bcntD = (int*)p;                  p += 256 * 4;
    int* bbaseS= (int*)p;                  p += 256 * 4;
    int* bbaseD= (int*)p;                  p += 256 * 4;
    int* gcurS = (int*)p;                  p += 256 * 4;
    int* gcurD = (int*)p;                  p += 256 * 4;

    // W prep (independent)
    k_prepW<128><<<64, 256, 0, stream>>>(W1, W1h, W1l);
    k_prepW<128><<<64, 256, 0, stream>>>(W2, W2h, W2l);
    k_prepW<64><<<32, 256, 0, stream>>>(W3, W3h, W3l);

    // bucketed degree/CSR pipeline (no per-edge global atomics)
    hipMemsetAsync(bcntS, 0, 2 * 256 * 4, stream);
    k_bhist2<<<192, 256, 0, stream>>>(src, dst, bcntS, bcntD, E);
    k_bscan2<<<1, 256, 0, stream>>>(bcntS, bcntD, bbaseS, gcurS, bbaseD, gcurD);
    k_bscatter3<<<(E + CH - 1) / CH, 256, 0, stream>>>(src, dst, gcurD, gcurS, tmpD, tmpS, E);
    k_cntS<<<NB, 256, 0, stream>>>(bbaseS, bcntS, tmpS, ns, N);
    k_csrD<<<NB, 256, 0, stream>>>(bbaseD, bcntD, tmpD, degI, nd, rowp, srcIdx, N);

    const int gemm_grid  = (N + 63) / 64;
    const int agg64      = (N + 31) / 32;

    // ---- layer 1: h1 = (x*ns) @ W1 ----
    k_gemm_mfma<128><<<gemm_grid, 256, 0, stream>>>(x, W1h, W1l, ns, bufA, N);

    // ---- layer 2 fused: h2 = relu(Agg(h1)*nd + b1)*ns @ W2 ----
    k_gemm_gather<128><<<gemm_grid, 256, 0, stream>>>(rowp, degI, srcIdx, bufA,
        W2h, W2l, b1, ns, nd, bufB, N);

    // ---- layer 3 fused: h3 = relu(Agg(h2)*nd + b2)*ns @ W3 ----
    k_gemm_gather<64><<<gemm_grid, 256, 0, stream>>>(rowp, degI, srcIdx, bufB,
        W3h, W3l, b2, ns, nd, bufA, N);

    // ---- final: out = Agg(h3)*nd + b3 ----
    k_agg_final<64><<<agg64, 256, 0, stream>>>(rowp, degI, srcIdx, bufA, nd, b3, out, N);
}

// Round 12
// 307.841 us; speedup vs baseline: 1.0827x; 1.0827x over previous
//
#include <hip/hip_runtime.h>

#define NN 100000
#define NB 196            // ceil(NN / 512) buckets of 512 nodes
#define CH 4096           // edges per block in k_bscatter3

typedef short short8 __attribute__((ext_vector_type(8)));
typedef unsigned short u16x8 __attribute__((ext_vector_type(8)));
typedef float f32x4 __attribute__((ext_vector_type(4)));

__device__ inline unsigned short f2bf(float x) {
    unsigned u = __float_as_uint(x);
    unsigned r = (u + 0x7FFF + ((u >> 16) & 1)) >> 16;
    return (unsigned short)r;
}
__device__ inline float bf2f(unsigned short h) {
    return __uint_as_float(((unsigned)h) << 16);
}

// ---------------- bucket histograms (src & dst) via LDS ----------------
__global__ __launch_bounds__(256) void k_bhist2(const int* __restrict__ src,
    const int* __restrict__ dst, int* __restrict__ bcntS, int* __restrict__ bcntD, int E)
{
    __shared__ int hs[NB], hd[NB];
    int t = threadIdx.x;
    if (t < NB) { hs[t] = 0; hd[t] = 0; }
    __syncthreads();
    int stride = gridDim.x * 256;
    for (int e = blockIdx.x * 256 + t; e < E; e += stride) {
        atomicAdd(&hs[src[e] >> 9], 1);
        atomicAdd(&hd[dst[e] >> 9], 1);
    }
    __syncthreads();
    if (t < NB) {
        if (hs[t]) atomicAdd(&bcntS[t], hs[t]);
        if (hd[t]) atomicAdd(&bcntD[t], hd[t]);
    }
}

// ---------------- exact bucket scans (dense tmp layout) ----------------
__global__ __launch_bounds__(256) void k_bscan2(const int* __restrict__ bcntS,
    const int* __restrict__ bcntD, int* __restrict__ bbaseS, int* __restrict__ gcurS,
    int* __restrict__ bbaseD, int* __restrict__ gcurD)
{
    __shared__ int s[256];
    int t = threadIdx.x;
    int cD = (t < NB) ? bcntD[t] : 0;
    int cS = (t < NB) ? bcntS[t] : 0;

    int v = cD;
    s[t] = v;
    __syncthreads();
#pragma unroll
    for (int off = 1; off < 256; off <<= 1) {
        int x = (t >= off) ? s[t - off] : 0;
        __syncthreads(); s[t] += x; __syncthreads();
    }
    if (t < NB) { int e = s[t] - v; bbaseD[t] = e; gcurD[t] = e; }
    __syncthreads();

    v = cS;
    s[t] = v;
    __syncthreads();
#pragma unroll
    for (int off = 1; off < 256; off <<= 1) {
        int x = (t >= off) ? s[t - off] : 0;
        __syncthreads(); s[t] += x; __syncthreads();
    }
    if (t < NB) { int e = s[t] - v; bbaseS[t] = e; gcurS[t] = e; }
}

// ---------------- one-shot counting-claim bucket scatter ----------------
__global__ __launch_bounds__(256) void k_bscatter3(const int* __restrict__ src,
    const int* __restrict__ dst, int* __restrict__ gcurD, int* __restrict__ gcurS,
    unsigned* __restrict__ tmpD, unsigned* __restrict__ tmpS, int E)
{
    __shared__ int cntD[NB], cntS[NB];
    __shared__ int runD[NB], runS[NB];
    int t = threadIdx.x;
    if (t < NB) { cntD[t] = 0; cntS[t] = 0; }
    __syncthreads();

    const int e0 = blockIdx.x * CH;
    int sv[16], dv[16];
    int offD[16], offS[16];
#pragma unroll
    for (int i = 0; i < 16; i++) {
        int e = e0 + i * 256 + t;
        if (e < E) { sv[i] = src[e]; dv[i] = dst[e]; }
    }
#pragma unroll
    for (int i = 0; i < 16; i++) {
        int e = e0 + i * 256 + t;
        if (e < E) {
            offD[i] = atomicAdd(&cntD[dv[i] >> 9], 1);
            offS[i] = atomicAdd(&cntS[sv[i] >> 9], 1);
        }
    }
    __syncthreads();
    if (t < NB) {
        int c = cntD[t];
        if (c) runD[t] = atomicAdd(&gcurD[t], c);
        c = cntS[t];
        if (c) runS[t] = atomicAdd(&gcurS[t], c);
    }
    __syncthreads();
#pragma unroll
    for (int i = 0; i < 16; i++) {
        int e = e0 + i * 256 + t;
        if (e < E) {
            int bD = dv[i] >> 9;
            tmpD[runD[bD] + offD[i]] = (unsigned)sv[i] | ((unsigned)(dv[i] & 511) << 17);
            int bS = sv[i] >> 9;
            tmpS[runS[bS] + offS[i]] = (unsigned)(sv[i] & 511);
        }
    }
}

// ---------------- src-bucket count -> ns ----------------
__global__ __launch_bounds__(256) void k_cntS(const int* __restrict__ bbaseS,
    const int* __restrict__ bcntS, const unsigned* __restrict__ tmpS,
    float* __restrict__ ns, int N)
{
    __shared__ int cnt[512];
    int b = blockIdx.x, t = threadIdx.x;
    cnt[t] = 0; cnt[t + 256] = 0;
    __syncthreads();
    int beg = bbaseS[b], end = beg + bcntS[b];
    for (int e = beg + t; e < end; e += 256)
        atomicAdd(&cnt[tmpS[e]], 1);
    __syncthreads();
    int nb = b << 9;
    for (int i = t; i < 512; i += 256) {
        int n = nb + i;
        if (n < N) ns[n] = rsqrtf(fmaxf((float)cnt[i], 1.0f));
    }
}

// ---------------- dst-bucket: degI + nd + rowptr + src-ordered CSR fill ----------------
__global__ __launch_bounds__(256) void k_csrD(const int* __restrict__ bbaseD,
    const int* __restrict__ bcntD, const unsigned* __restrict__ tmpD,
    int* __restrict__ degI, float* __restrict__ nd,
    int* __restrict__ rowptr, int* __restrict__ srcIdx, int N)
{
    __shared__ int cnt[8192];      // [dlocal][16 src-parts], 32 KB
    __shared__ int sblk[256];
    int b = blockIdx.x, t = threadIdx.x;
    for (int i = t; i < 8192; i += 256) cnt[i] = 0;
    __syncthreads();
    int beg = bbaseD[b], end = beg + bcntD[b];
    for (int e = beg + t; e < end; e += 256) {
        unsigned v = tmpD[e];
        int dl = v >> 17;
        int s  = (int)(v & 0x1FFFFu);
        atomicAdd(&cnt[(dl << 4) | (s >> 13)], 1);
    }
    __syncthreads();
    int loc[32];
    int sum = 0;
#pragma unroll
    for (int i = 0; i < 32; i++) { loc[i] = sum; sum += cnt[t * 32 + i]; }
    sblk[t] = sum;
    __syncthreads();
#pragma unroll
    for (int off = 1; off < 256; off <<= 1) {
        int x = (t >= off) ? sblk[t - off] : 0;
        __syncthreads(); sblk[t] += x; __syncthreads();
    }
    int base = beg + sblk[t] - sum;
    int v0 = loc[16];
    int v1 = sum - loc[16];
    int nb = b << 9;
    int n0 = nb + 2 * t, n1 = n0 + 1;
    if (n0 < N) { rowptr[n0] = base;           degI[n0] = v0; nd[n0] = rsqrtf(fmaxf((float)v0, 1.f)); }
    if (n1 < N) { rowptr[n1] = base + loc[16]; degI[n1] = v1; nd[n1] = rsqrtf(fmaxf((float)v1, 1.f)); }
#pragma unroll
    for (int i = 0; i < 32; i++) cnt[t * 32 + i] = base + loc[i];
    __syncthreads();
    for (int e = beg + t; e < end; e += 256) {
        unsigned v = tmpD[e];
        int dl = v >> 17;
        int s  = (int)(v & 0x1FFFFu);
        int pos = atomicAdd(&cnt[(dl << 4) | (s >> 13)], 1);
        srcIdx[pos] = s;
    }
}

// ---------------- W prep: transpose + bf16 split + XOR-swizzle ----------------
template<int DOUT>
__global__ __launch_bounds__(256) void k_prepW(const float* __restrict__ W,
    unsigned short* __restrict__ Wh, unsigned short* __restrict__ Wl)
{
    int idx = blockIdx.x * 256 + threadIdx.x;
    if (idx >= 128 * DOUT) return;
    int c = idx % DOUT;
    int k = idx / DOUT;
    float w = W[idx];
    unsigned short hi = f2bf(w);
    unsigned short lo = f2bf(w - bf2f(hi));
    int boff = c * 256 + ((2 * k) ^ ((c & 7) << 4));
    *(unsigned short*)((char*)Wh + boff) = hi;
    *(unsigned short*)((char*)Wl + boff) = lo;
}

// ---------------- MFMA GEMM layer 1: out[n][:] = (x[n][:]*ns[n]) @ W  (f32 in, bf16 out) ----------------
template<int DOUT>
__global__ __launch_bounds__(256) void k_gemm_mfma(
    const float* __restrict__ in,
    const unsigned short* __restrict__ Wth, const unsigned short* __restrict__ Wtl,
    const float* __restrict__ ns,
    unsigned short* __restrict__ out, int N)
{
    constexpr int NT = DOUT / 16;
    __shared__ __align__(16) unsigned short Wh[DOUT * 128];
    __shared__ __align__(16) unsigned short Wl[DOUT * 128];

    const int t = threadIdx.x;
    const int w = t >> 6, l = t & 63;

#pragma unroll
    for (int i = 0; i < DOUT * 256 / 4096; i++) {
        int off = i * 4096 + t * 16;
        *(float4*)((char*)Wh + off) = *(const float4*)((const char*)Wth + off);
        *(float4*)((char*)Wl + off) = *(const float4*)((const char*)Wtl + off);
    }

    const int rl   = l & 15;
    const int kgrp = l >> 4;
    const int row  = blockIdx.x * 64 + w * 16 + rl;
    const int rowc = row < N ? row : N - 1;
    const float* arow = in + (size_t)rowc * 128;

    float av[4][8];
#pragma unroll
    for (int ks = 0; ks < 4; ks++) {
        int kb = ks * 32 + kgrp * 8;
        float4 v0 = *(const float4*)(arow + kb);
        float4 v1 = *(const float4*)(arow + kb + 4);
        av[ks][0] = v0.x; av[ks][1] = v0.y; av[ks][2] = v0.z; av[ks][3] = v0.w;
        av[ks][4] = v1.x; av[ks][5] = v1.y; av[ks][6] = v1.z; av[ks][7] = v1.w;
    }
    float nsv = ns[rowc];
    short8 Ah[4], Al[4];
#pragma unroll
    for (int ks = 0; ks < 4; ks++)
#pragma unroll
        for (int j = 0; j < 8; j++) {
            float v = av[ks][j] * nsv;
            unsigned short hi = f2bf(v);
            Ah[ks][j] = (short)hi;
            Al[ks][j] = (short)f2bf(v - bf2f(hi));
        }

    __syncthreads();

    f32x4 acc[NT];
#pragma unroll
    for (int tt = 0; tt < NT; tt++) acc[tt] = (f32x4){0.f, 0.f, 0.f, 0.f};

#pragma unroll
    for (int ks = 0; ks < 4; ks++) {
        int kbyte = ks * 64 + kgrp * 16;
#pragma unroll
        for (int tt = 0; tt < NT; tt++) {
            int c = tt * 16 + rl;
            int boff = c * 256 + (kbyte ^ ((c & 7) << 4));
            short8 Bh = *(short8*)((char*)Wh + boff);
            short8 Bl = *(short8*)((char*)Wl + boff);
            acc[tt] = __builtin_amdgcn_mfma_f32_16x16x32_bf16(Ah[ks], Bh, acc[tt], 0, 0, 0);
            acc[tt] = __builtin_amdgcn_mfma_f32_16x16x32_bf16(Al[ks], Bh, acc[tt], 0, 0, 0);
            acc[tt] = __builtin_amdgcn_mfma_f32_16x16x32_bf16(Ah[ks], Bl, acc[tt], 0, 0, 0);
        }
    }

    const int orow = blockIdx.x * 64 + w * 16 + kgrp * 4;
#pragma unroll
    for (int r = 0; r < 4; r++) {
        if (orow + r < N) {
#pragma unroll
            for (int tt = 0; tt < NT; tt++)
                out[(size_t)(orow + r) * DOUT + tt * 16 + rl] = f2bf(acc[tt][r]);
        }
    }
}

// ---------------- gather + epilogue -> bf16 A (barrier-free, k_agg shape) ----------------
// out[n][:] = bf16( relu(sum_e h[srcIdx[e]] * nd[n] + b[k]) * ns[n] )
__global__ __launch_bounds__(256) void k_agg_epi(
    const int* __restrict__ rowptr, const int* __restrict__ cnt,
    const int* __restrict__ srcIdx, const unsigned short* __restrict__ h,
    const float* __restrict__ nd, const float* __restrict__ ns,
    const float* __restrict__ bias,
    unsigned short* __restrict__ out, int N)
{
    int t = threadIdx.x;
    int node = blockIdx.x * 16 + (t >> 4);
    if (node >= N) return;
    int c = (t & 15) * 8;

    int beg = rowptr[node];
    int end = beg + cnt[node];
    float acc[8] = {0.f, 0.f, 0.f, 0.f, 0.f, 0.f, 0.f, 0.f};
    int e = beg;
    for (; e + 1 < end; e += 2) {
        int s0 = srcIdx[e], s1 = srcIdx[e + 1];
        u16x8 v0 = *(const u16x8*)&h[(size_t)s0 * 128 + c];
        u16x8 v1 = *(const u16x8*)&h[(size_t)s1 * 128 + c];
#pragma unroll
        for (int j = 0; j < 8; j++) acc[j] += bf2f(v0[j]) + bf2f(v1[j]);
    }
    if (e < end) {
        int s0 = srcIdx[e];
        u16x8 v0 = *(const u16x8*)&h[(size_t)s0 * 128 + c];
#pragma unroll
        for (int j = 0; j < 8; j++) acc[j] += bf2f(v0[j]);
    }
    float ndv = nd[node], nsv = ns[node];
    float4 b0 = *(const float4*)(bias + c);
    float4 b1 = *(const float4*)(bias + c + 4);
    float bb[8] = {b0.x, b0.y, b0.z, b0.w, b1.x, b1.y, b1.z, b1.w};
    u16x8 o;
#pragma unroll
    for (int j = 0; j < 8; j++)
        o[j] = f2bf(fmaxf(acc[j] * ndv + bb[j], 0.f) * nsv);
    *(u16x8*)&out[(size_t)node * 128 + c] = o;
}

// ---------------- bf16-A MFMA GEMM: out = A @ W (A bf16 N×128, W hi/lo) ----------------
template<int DOUT>
__global__ __launch_bounds__(256) void k_gemm_bf(
    const unsigned short* __restrict__ in,
    const unsigned short* __restrict__ Wth, const unsigned short* __restrict__ Wtl,
    unsigned short* __restrict__ out, int N)
{
    constexpr int NT = DOUT / 16;
    __shared__ __align__(16) unsigned short Wh[DOUT * 128];
    __shared__ __align__(16) unsigned short Wl[DOUT * 128];

    const int t = threadIdx.x;
    const int w = t >> 6, l = t & 63;

#pragma unroll
    for (int i = 0; i < DOUT * 256 / 4096; i++) {
        int off = i * 4096 + t * 16;
        *(float4*)((char*)Wh + off) = *(const float4*)((const char*)Wth + off);
        *(float4*)((char*)Wl + off) = *(const float4*)((const char*)Wtl + off);
    }

    const int rl   = l & 15;
    const int kgrp = l >> 4;
    const int row  = blockIdx.x * 64 + w * 16 + rl;
    const int rowc = row < N ? row : N - 1;
    const unsigned short* arow = in + (size_t)rowc * 128;

    short8 Ah[4];
#pragma unroll
    for (int ks = 0; ks < 4; ks++)
        Ah[ks] = *(const short8*)(arow + ks * 32 + kgrp * 8);

    __syncthreads();

    f32x4 acc[NT];
#pragma unroll
    for (int tt = 0; tt < NT; tt++) acc[tt] = (f32x4){0.f, 0.f, 0.f, 0.f};

#pragma unroll
    for (int ks = 0; ks < 4; ks++) {
        int kbyte = ks * 64 + kgrp * 16;
#pragma unroll
        for (int tt = 0; tt < NT; tt++) {
            int c = tt * 16 + rl;
            int boff = c * 256 + (kbyte ^ ((c & 7) << 4));
            short8 Bh = *(short8*)((char*)Wh + boff);
            short8 Bl = *(short8*)((char*)Wl + boff);
            acc[tt] = __builtin_amdgcn_mfma_f32_16x16x32_bf16(Ah[ks], Bh, acc[tt], 0, 0, 0);
            acc[tt] = __builtin_amdgcn_mfma_f32_16x16x32_bf16(Ah[ks], Bl, acc[tt], 0, 0, 0);
        }
    }

    const int orow = blockIdx.x * 64 + w * 16 + kgrp * 4;
#pragma unroll
    for (int r = 0; r < 4; r++) {
        if (orow + r < N) {
#pragma unroll
            for (int tt = 0; tt < NT; tt++)
                out[(size_t)(orow + r) * DOUT + tt * 16 + rl] = f2bf(acc[tt][r]);
        }
    }
}

// ---------------- final aggregation (bf16 gather, f32 accumulate, epilogue) ----------------
template<int D>
__global__ __launch_bounds__(256) void k_agg_final(
    const int* __restrict__ rowptr, const int* __restrict__ cnt,
    const int* __restrict__ srcIdx, const unsigned short* __restrict__ h,
    const float* __restrict__ nd, const float* __restrict__ b3,
    float* __restrict__ m, int N)
{
    constexpr int TPN = D / 8;
    constexpr int NPB = 256 / TPN;
    int t = threadIdx.x;
    int node = blockIdx.x * NPB + t / TPN;
    if (node >= N) return;
    int c = (t % TPN) * 8;

    int beg = rowptr[node];
    int end = beg + cnt[node];
    float acc[8] = {0.f, 0.f, 0.f, 0.f, 0.f, 0.f, 0.f, 0.f};
    int e = beg;
    for (; e + 1 < end; e += 2) {
        int s0 = srcIdx[e], s1 = srcIdx[e + 1];
        u16x8 v0 = *(const u16x8*)&h[(size_t)s0 * D + c];
        u16x8 v1 = *(const u16x8*)&h[(size_t)s1 * D + c];
#pragma unroll
        for (int j = 0; j < 8; j++) acc[j] += bf2f(v0[j]) + bf2f(v1[j]);
    }
    if (e < end) {
        int s0 = srcIdx[e];
        u16x8 v0 = *(const u16x8*)&h[(size_t)s0 * D + c];
#pragma unroll
        for (int j = 0; j < 8; j++) acc[j] += bf2f(v0[j]);
    }
    float ndv = nd[node];
#pragma unroll
    for (int j = 0; j < 8; j++) acc[j] = acc[j] * ndv + b3[c + j];
    float4* mp = (float4*)&m[(size_t)node * D + c];
    mp[0] = make_float4(acc[0], acc[1], acc[2], acc[3]);
    mp[1] = make_float4(acc[4], acc[5], acc[6], acc[7]);
}

extern "C" void kernel_launch(void* const* d_in, const int* in_sizes, int n_in,
                              void* d_out, int out_size, void* d_ws, size_t ws_size,
                              hipStream_t stream) {
    const float* x  = (const float*)d_in[0];
    const int*   src = (const int*)d_in[1];
    const int*   dst = (const int*)d_in[2];
    const float* W1 = (const float*)d_in[3];
    const float* b1 = (const float*)d_in[4];
    const float* W2 = (const float*)d_in[5];
    const float* b2 = (const float*)d_in[6];
    const float* W3 = (const float*)d_in[7];
    const float* b3 = (const float*)d_in[8];
    float* out = (float*)d_out;

    const int N = NN;
    const int E = in_sizes[1];

    char* ws = (char*)d_ws;
    unsigned short* bufA = (unsigned short*)ws;                 // h1 / h2 / h3 (aliases tmpD)
    unsigned short* bufB = (unsigned short*)(ws + (size_t)N * 128 * 4); // A' handoff (aliases tmpS)
    unsigned* tmpD = (unsigned*)bufA;                           // consumed by k_csrD before gemm1 writes bufA
    unsigned* tmpS = (unsigned*)bufB;                           // consumed by k_cntS before agg_epi writes bufB
    char*  p     = ws + (size_t)N * 128 * 4 * 2;
    float* ns    = (float*)p;              p += (size_t)N * 4;
    float* nd    = (float*)p;              p += (size_t)N * 4;
    int*   degI  = (int*)p;                p += (size_t)N * 4;
    int*   rowp  = (int*)p;                p += (size_t)N * 4;
    int*   srcIdx= (int*)p;                p += (size_t)E * 4;
    unsigned short* W1h = (unsigned short*)p; p += 128 * 128 * 2;
    unsigned short* W1l = (unsigned short*)p; p += 128 * 128 * 2;
    unsigned short* W2h = (unsigned short*)p; p += 128 * 128 * 2;
    unsigned short* W2l = (unsigned short*)p; p += 128 * 128 * 2;
    unsigned short* W3h = (unsigned short*)p; p += 64 * 128 * 2;
    unsigned short* W3l = (unsigned short*)p; p += 64 * 128 * 2;
    int* bcntS = (int*)p;                  p += 256 * 4;
    int* bcntD = (int*)p;                  p += 256 * 4;
    int* bbaseS= (int*)p;                  p += 256 * 4;
    int* bbaseD= (int*)p;                  p += 256 * 4;
    int* gcurS = (int*)p;                  p += 256 * 4;
    int* gcurD = (int*)p;                  p += 256 * 4;
    unsigned short* bufC = (unsigned short*)p;                  // h2 (N*128 bf16)

    // W prep (independent)
    k_prepW<128><<<64, 256, 0, stream>>>(W1, W1h, W1l);
    k_prepW<128><<<64, 256, 0, stream>>>(W2, W2h, W2l);
    k_prepW<64><<<32, 256, 0, stream>>>(W3, W3h, W3l);

    // bucketed degree/CSR pipeline (no per-edge global atomics)
    hipMemsetAsync(bcntS, 0, 2 * 256 * 4, stream);
    k_bhist2<<<192, 256, 0, stream>>>(src, dst, bcntS, bcntD, E);
    k_bscan2<<<1, 256, 0, stream>>>(bcntS, bcntD, bbaseS, gcurS, bbaseD, gcurD);
    k_bscatter3<<<(E + CH - 1) / CH, 256, 0, stream>>>(src, dst, gcurD, gcurS, tmpD, tmpS, E);
    k_cntS<<<NB, 256, 0, stream>>>(bbaseS, bcntS, tmpS, ns, N);
    k_csrD<<<NB, 256, 0, stream>>>(bbaseD, bcntD, tmpD, degI, nd, rowp, srcIdx, N);

    const int gemm_grid = (N + 63) / 64;
    const int agg16     = (N + 15) / 16;
    const int agg64     = (N + 31) / 32;

    // ---- layer 1: h1 = (x*ns) @ W1 -> bufA ----
    k_gemm_mfma<128><<<gemm_grid, 256, 0, stream>>>(x, W1h, W1l, ns, bufA, N);

    // ---- layer 2: A2 = epi(Agg(h1)) -> bufB ; h2 = A2 @ W2 -> bufC ----
    k_agg_epi<<<agg16, 256, 0, stream>>>(rowp, degI, srcIdx, bufA, nd, ns, b1, bufB, N);
    k_gemm_bf<128><<<gemm_grid, 256, 0, stream>>>(bufB, W2h, W2l, bufC, N);

    // ---- layer 3: A3 = epi(Agg(h2)) -> bufB ; h3 = A3 @ W3 -> bufA ----
    k_agg_epi<<<agg16, 256, 0, stream>>>(rowp, degI, srcIdx, bufC, nd, ns, b2, bufB, N);
    k_gemm_bf<64><<<gemm_grid, 256, 0, stream>>>(bufB, W3h, W3l, bufA, N);

    // ---- final: out = Agg(h3)*nd + b3 ----
    k_agg_final<64><<<agg64, 256, 0, stream>>>(rowp, degI, srcIdx, bufA, nd, b3, out, N);
}

// Round 13
// 284.621 us; speedup vs baseline: 1.1711x; 1.0816x over previous
//
#include <hip/hip_runtime.h>

#define NN 100000
#define NB 196            // ceil(NN / 512) buckets of 512 nodes
#define CH 4096           // edges per block in k_bscatter3
#define HB 192            // histogram blocks

typedef short short8 __attribute__((ext_vector_type(8)));
typedef unsigned short u16x8 __attribute__((ext_vector_type(8)));
typedef float f32x4 __attribute__((ext_vector_type(4)));

__device__ inline unsigned short f2bf(float x) {
    unsigned u = __float_as_uint(x);
    unsigned r = (u + 0x7FFF + ((u >> 16) & 1)) >> 16;
    return (unsigned short)r;
}
__device__ inline float bf2f(unsigned short h) {
    return __uint_as_float(((unsigned)h) << 16);
}

// ---------------- bucket histograms: per-block partials (no global atomics) ----------------
__global__ __launch_bounds__(256) void k_bhist2p(const int* __restrict__ src,
    const int* __restrict__ dst, int* __restrict__ partS, int* __restrict__ partD, int E)
{
    __shared__ int hs[NB], hd[NB];
    int t = threadIdx.x;
    if (t < NB) { hs[t] = 0; hd[t] = 0; }
    __syncthreads();
    int stride = HB * 256;
    for (int e = blockIdx.x * 256 + t; e < E; e += stride) {
        atomicAdd(&hs[src[e] >> 9], 1);
        atomicAdd(&hd[dst[e] >> 9], 1);
    }
    __syncthreads();
    partS[blockIdx.x * 256 + t] = (t < NB) ? hs[t] : 0;
    partD[blockIdx.x * 256 + t] = (t < NB) ? hd[t] : 0;
}

// ---------------- reduce partials + exact bucket scans ----------------
__global__ __launch_bounds__(256) void k_bscan2(const int* __restrict__ partS,
    const int* __restrict__ partD,
    int* __restrict__ bcntS, int* __restrict__ bcntD,
    int* __restrict__ bbaseS, int* __restrict__ gcurS,
    int* __restrict__ bbaseD, int* __restrict__ gcurD)
{
    __shared__ int s[256];
    int t = threadIdx.x;
    int cS = 0, cD = 0;
    for (int i = 0; i < HB; i++) {
        cS += partS[i * 256 + t];
        cD += partD[i * 256 + t];
    }
    if (t < NB) { bcntS[t] = cS; bcntD[t] = cD; }

    int v = cD;
    s[t] = v;
    __syncthreads();
#pragma unroll
    for (int off = 1; off < 256; off <<= 1) {
        int x = (t >= off) ? s[t - off] : 0;
        __syncthreads(); s[t] += x; __syncthreads();
    }
    if (t < NB) { int e = s[t] - v; bbaseD[t] = e; gcurD[t] = e; }
    __syncthreads();

    v = cS;
    s[t] = v;
    __syncthreads();
#pragma unroll
    for (int off = 1; off < 256; off <<= 1) {
        int x = (t >= off) ? s[t - off] : 0;
        __syncthreads(); s[t] += x; __syncthreads();
    }
    if (t < NB) { int e = s[t] - v; bbaseS[t] = e; gcurS[t] = e; }
}

// ---------------- one-shot counting-claim bucket scatter ----------------
__global__ __launch_bounds__(256) void k_bscatter3(const int* __restrict__ src,
    const int* __restrict__ dst, int* __restrict__ gcurD, int* __restrict__ gcurS,
    unsigned* __restrict__ tmpD, unsigned* __restrict__ tmpS, int E)
{
    __shared__ int cntD[NB], cntS[NB];
    __shared__ int runD[NB], runS[NB];
    int t = threadIdx.x;
    if (t < NB) { cntD[t] = 0; cntS[t] = 0; }
    __syncthreads();

    const int e0 = blockIdx.x * CH;
    int sv[16], dv[16];
    int offD[16], offS[16];
#pragma unroll
    for (int i = 0; i < 16; i++) {
        int e = e0 + i * 256 + t;
        if (e < E) { sv[i] = src[e]; dv[i] = dst[e]; }
    }
#pragma unroll
    for (int i = 0; i < 16; i++) {
        int e = e0 + i * 256 + t;
        if (e < E) {
            offD[i] = atomicAdd(&cntD[dv[i] >> 9], 1);
            offS[i] = atomicAdd(&cntS[sv[i] >> 9], 1);
        }
    }
    __syncthreads();
    if (t < NB) {
        int c = cntD[t];
        if (c) runD[t] = atomicAdd(&gcurD[t], c);
        c = cntS[t];
        if (c) runS[t] = atomicAdd(&gcurS[t], c);
    }
    __syncthreads();
#pragma unroll
    for (int i = 0; i < 16; i++) {
        int e = e0 + i * 256 + t;
        if (e < E) {
            int bD = dv[i] >> 9;
            tmpD[runD[bD] + offD[i]] = (unsigned)sv[i] | ((unsigned)(dv[i] & 511) << 17);
            int bS = sv[i] >> 9;
            tmpS[runS[bS] + offS[i]] = (unsigned)(sv[i] & 511);
        }
    }
}

// ---------------- merged build: blocks [0,NB) = dst CSR ; [NB,2NB) = src count -> ns ----------------
__global__ __launch_bounds__(256) void k_build(
    const int* __restrict__ bbaseD, const int* __restrict__ bcntD, const unsigned* __restrict__ tmpD,
    const int* __restrict__ bbaseS, const int* __restrict__ bcntS, const unsigned* __restrict__ tmpS,
    int* __restrict__ degI, float* __restrict__ nd, float* __restrict__ ns,
    int* __restrict__ rowptr, int* __restrict__ srcIdx, int N)
{
    __shared__ int cnt[8192];
    __shared__ int sblk[256];
    int t = threadIdx.x;

    if (blockIdx.x >= NB) {
        // ---- src-bucket count -> ns ----
        int b = blockIdx.x - NB;
        cnt[t] = 0; cnt[t + 256] = 0;
        __syncthreads();
        int beg = bbaseS[b], end = beg + bcntS[b];
        for (int e = beg + t; e < end; e += 256)
            atomicAdd(&cnt[tmpS[e]], 1);
        __syncthreads();
        int nb = b << 9;
        for (int i = t; i < 512; i += 256) {
            int n = nb + i;
            if (n < N) ns[n] = rsqrtf(fmaxf((float)cnt[i], 1.0f));
        }
        return;
    }

    // ---- dst-bucket: degI + nd + rowptr + src-ordered CSR fill ----
    int b = blockIdx.x;
    for (int i = t; i < 8192; i += 256) cnt[i] = 0;
    __syncthreads();
    int beg = bbaseD[b], end = beg + bcntD[b];
    for (int e = beg + t; e < end; e += 256) {
        unsigned v = tmpD[e];
        int dl = v >> 17;
        int s  = (int)(v & 0x1FFFFu);
        atomicAdd(&cnt[(dl << 4) | (s >> 13)], 1);
    }
    __syncthreads();
    int loc[32];
    int sum = 0;
#pragma unroll
    for (int i = 0; i < 32; i++) { loc[i] = sum; sum += cnt[t * 32 + i]; }
    sblk[t] = sum;
    __syncthreads();
#pragma unroll
    for (int off = 1; off < 256; off <<= 1) {
        int x = (t >= off) ? sblk[t - off] : 0;
        __syncthreads(); sblk[t] += x; __syncthreads();
    }
    int base = beg + sblk[t] - sum;
    int v0 = loc[16];
    int v1 = sum - loc[16];
    int nb = b << 9;
    int n0 = nb + 2 * t, n1 = n0 + 1;
    if (n0 < N) { rowptr[n0] = base;           degI[n0] = v0; nd[n0] = rsqrtf(fmaxf((float)v0, 1.f)); }
    if (n1 < N) { rowptr[n1] = base + loc[16]; degI[n1] = v1; nd[n1] = rsqrtf(fmaxf((float)v1, 1.f)); }
#pragma unroll
    for (int i = 0; i < 32; i++) cnt[t * 32 + i] = base + loc[i];
    __syncthreads();
    for (int e = beg + t; e < end; e += 256) {
        unsigned v = tmpD[e];
        int dl = v >> 17;
        int s  = (int)(v & 0x1FFFFu);
        int pos = atomicAdd(&cnt[(dl << 4) | (s >> 13)], 1);
        srcIdx[pos] = s;
    }
}

// ---------------- W prep (all three weights, one launch) ----------------
__global__ __launch_bounds__(256) void k_prepW_all(
    const float* __restrict__ W1, const float* __restrict__ W2, const float* __restrict__ W3,
    unsigned short* __restrict__ W1h, unsigned short* __restrict__ W1l,
    unsigned short* __restrict__ W2h, unsigned short* __restrict__ W2l,
    unsigned short* __restrict__ W3h, unsigned short* __restrict__ W3l)
{
    int b = blockIdx.x;
    const float* W; unsigned short *Wh, *Wl; int DOUT, idx;
    if (b < 64)       { W = W1; Wh = W1h; Wl = W1l; DOUT = 128; idx = b * 256 + threadIdx.x; }
    else if (b < 128) { W = W2; Wh = W2h; Wl = W2l; DOUT = 128; idx = (b - 64) * 256 + threadIdx.x; }
    else              { W = W3; Wh = W3h; Wl = W3l; DOUT = 64;  idx = (b - 128) * 256 + threadIdx.x; }
    if (idx >= 128 * DOUT) return;
    int c = idx % DOUT;
    int k = idx / DOUT;
    float w = W[idx];
    unsigned short hi = f2bf(w);
    unsigned short lo = f2bf(w - bf2f(hi));
    int boff = c * 256 + ((2 * k) ^ ((c & 7) << 4));
    *(unsigned short*)((char*)Wh + boff) = hi;
    *(unsigned short*)((char*)Wl + boff) = lo;
}

// ---------------- MFMA GEMM layer 1: out[n][:] = (x[n][:]*ns[n]) @ W  (f32 in, bf16 out) ----------------
template<int DOUT>
__global__ __launch_bounds__(256) void k_gemm_mfma(
    const float* __restrict__ in,
    const unsigned short* __restrict__ Wth, const unsigned short* __restrict__ Wtl,
    const float* __restrict__ ns,
    unsigned short* __restrict__ out, int N)
{
    constexpr int NT = DOUT / 16;
    __shared__ __align__(16) unsigned short Wh[DOUT * 128];
    __shared__ __align__(16) unsigned short Wl[DOUT * 128];

    const int t = threadIdx.x;
    const int w = t >> 6, l = t & 63;

#pragma unroll
    for (int i = 0; i < DOUT * 256 / 4096; i++) {
        int off = i * 4096 + t * 16;
        *(float4*)((char*)Wh + off) = *(const float4*)((const char*)Wth + off);
        *(float4*)((char*)Wl + off) = *(const float4*)((const char*)Wtl + off);
    }

    const int rl   = l & 15;
    const int kgrp = l >> 4;
    const int row  = blockIdx.x * 64 + w * 16 + rl;
    const int rowc = row < N ? row : N - 1;
    const float* arow = in + (size_t)rowc * 128;

    float av[4][8];
#pragma unroll
    for (int ks = 0; ks < 4; ks++) {
        int kb = ks * 32 + kgrp * 8;
        float4 v0 = *(const float4*)(arow + kb);
        float4 v1 = *(const float4*)(arow + kb + 4);
        av[ks][0] = v0.x; av[ks][1] = v0.y; av[ks][2] = v0.z; av[ks][3] = v0.w;
        av[ks][4] = v1.x; av[ks][5] = v1.y; av[ks][6] = v1.z; av[ks][7] = v1.w;
    }
    float nsv = ns[rowc];
    short8 Ah[4], Al[4];
#pragma unroll
    for (int ks = 0; ks < 4; ks++)
#pragma unroll
        for (int j = 0; j < 8; j++) {
            float v = av[ks][j] * nsv;
            unsigned short hi = f2bf(v);
            Ah[ks][j] = (short)hi;
            Al[ks][j] = (short)f2bf(v - bf2f(hi));
        }

    __syncthreads();

    f32x4 acc[NT];
#pragma unroll
    for (int tt = 0; tt < NT; tt++) acc[tt] = (f32x4){0.f, 0.f, 0.f, 0.f};

#pragma unroll
    for (int ks = 0; ks < 4; ks++) {
        int kbyte = ks * 64 + kgrp * 16;
#pragma unroll
        for (int tt = 0; tt < NT; tt++) {
            int c = tt * 16 + rl;
            int boff = c * 256 + (kbyte ^ ((c & 7) << 4));
            short8 Bh = *(short8*)((char*)Wh + boff);
            short8 Bl = *(short8*)((char*)Wl + boff);
            acc[tt] = __builtin_amdgcn_mfma_f32_16x16x32_bf16(Ah[ks], Bh, acc[tt], 0, 0, 0);
            acc[tt] = __builtin_amdgcn_mfma_f32_16x16x32_bf16(Al[ks], Bh, acc[tt], 0, 0, 0);
            acc[tt] = __builtin_amdgcn_mfma_f32_16x16x32_bf16(Ah[ks], Bl, acc[tt], 0, 0, 0);
        }
    }

    const int orow = blockIdx.x * 64 + w * 16 + kgrp * 4;
#pragma unroll
    for (int r = 0; r < 4; r++) {
        if (orow + r < N) {
#pragma unroll
            for (int tt = 0; tt < NT; tt++)
                out[(size_t)(orow + r) * DOUT + tt * 16 + rl] = f2bf(acc[tt][r]);
        }
    }
}

// ---------------- gather + epilogue -> bf16 A (barrier-free, 4-deep unroll) ----------------
__global__ __launch_bounds__(256) void k_agg_epi(
    const int* __restrict__ rowptr, const int* __restrict__ cnt,
    const int* __restrict__ srcIdx, const unsigned short* __restrict__ h,
    const float* __restrict__ nd, const float* __restrict__ ns,
    const float* __restrict__ bias,
    unsigned short* __restrict__ out, int N)
{
    int t = threadIdx.x;
    int node = blockIdx.x * 16 + (t >> 4);
    if (node >= N) return;
    int c = (t & 15) * 8;

    int beg = rowptr[node];
    int end = beg + cnt[node];
    float acc[8] = {0.f, 0.f, 0.f, 0.f, 0.f, 0.f, 0.f, 0.f};
    int e = beg;
    for (; e + 3 < end; e += 4) {
        int s0 = srcIdx[e], s1 = srcIdx[e + 1], s2 = srcIdx[e + 2], s3 = srcIdx[e + 3];
        u16x8 v0 = *(const u16x8*)&h[(size_t)s0 * 128 + c];
        u16x8 v1 = *(const u16x8*)&h[(size_t)s1 * 128 + c];
        u16x8 v2 = *(const u16x8*)&h[(size_t)s2 * 128 + c];
        u16x8 v3 = *(const u16x8*)&h[(size_t)s3 * 128 + c];
#pragma unroll
        for (int j = 0; j < 8; j++)
            acc[j] += (bf2f(v0[j]) + bf2f(v1[j])) + (bf2f(v2[j]) + bf2f(v3[j]));
    }
    for (; e < end; e++) {
        int s0 = srcIdx[e];
        u16x8 v0 = *(const u16x8*)&h[(size_t)s0 * 128 + c];
#pragma unroll
        for (int j = 0; j < 8; j++) acc[j] += bf2f(v0[j]);
    }
    float ndv = nd[node], nsv = ns[node];
    float4 b0 = *(const float4*)(bias + c);
    float4 b1 = *(const float4*)(bias + c + 4);
    float bb[8] = {b0.x, b0.y, b0.z, b0.w, b1.x, b1.y, b1.z, b1.w};
    u16x8 o;
#pragma unroll
    for (int j = 0; j < 8; j++)
        o[j] = f2bf(fmaxf(acc[j] * ndv + bb[j], 0.f) * nsv);
    *(u16x8*)&out[(size_t)node * 128 + c] = o;
}

// ---------------- bf16-A MFMA GEMM: out = A @ W (A bf16 N×128, W hi/lo) ----------------
template<int DOUT>
__global__ __launch_bounds__(256) void k_gemm_bf(
    const unsigned short* __restrict__ in,
    const unsigned short* __restrict__ Wth, const unsigned short* __restrict__ Wtl,
    unsigned short* __restrict__ out, int N)
{
    constexpr int NT = DOUT / 16;
    __shared__ __align__(16) unsigned short Wh[DOUT * 128];
    __shared__ __align__(16) unsigned short Wl[DOUT * 128];

    const int t = threadIdx.x;
    const int w = t >> 6, l = t & 63;

#pragma unroll
    for (int i = 0; i < DOUT * 256 / 4096; i++) {
        int off = i * 4096 + t * 16;
        *(float4*)((char*)Wh + off) = *(const float4*)((const char*)Wth + off);
        *(float4*)((char*)Wl + off) = *(const float4*)((const char*)Wtl + off);
    }

    const int rl   = l & 15;
    const int kgrp = l >> 4;
    const int row  = blockIdx.x * 64 + w * 16 + rl;
    const int rowc = row < N ? row : N - 1;
    const unsigned short* arow = in + (size_t)rowc * 128;

    short8 Ah[4];
#pragma unroll
    for (int ks = 0; ks < 4; ks++)
        Ah[ks] = *(const short8*)(arow + ks * 32 + kgrp * 8);

    __syncthreads();

    f32x4 acc[NT];
#pragma unroll
    for (int tt = 0; tt < NT; tt++) acc[tt] = (f32x4){0.f, 0.f, 0.f, 0.f};

#pragma unroll
    for (int ks = 0; ks < 4; ks++) {
        int kbyte = ks * 64 + kgrp * 16;
#pragma unroll
        for (int tt = 0; tt < NT; tt++) {
            int c = tt * 16 + rl;
            int boff = c * 256 + (kbyte ^ ((c & 7) << 4));
            short8 Bh = *(short8*)((char*)Wh + boff);
            short8 Bl = *(short8*)((char*)Wl + boff);
            acc[tt] = __builtin_amdgcn_mfma_f32_16x16x32_bf16(Ah[ks], Bh, acc[tt], 0, 0, 0);
            acc[tt] = __builtin_amdgcn_mfma_f32_16x16x32_bf16(Ah[ks], Bl, acc[tt], 0, 0, 0);
        }
    }

    const int orow = blockIdx.x * 64 + w * 16 + kgrp * 4;
#pragma unroll
    for (int r = 0; r < 4; r++) {
        if (orow + r < N) {
#pragma unroll
            for (int tt = 0; tt < NT; tt++)
                out[(size_t)(orow + r) * DOUT + tt * 16 + rl] = f2bf(acc[tt][r]);
        }
    }
}

// ---------------- final aggregation (bf16 gather, f32 accumulate, epilogue, 4-deep) ----------------
template<int D>
__global__ __launch_bounds__(256) void k_agg_final(
    const int* __restrict__ rowptr, const int* __restrict__ cnt,
    const int* __restrict__ srcIdx, const unsigned short* __restrict__ h,
    const float* __restrict__ nd, const float* __restrict__ b3,
    float* __restrict__ m, int N)
{
    constexpr int TPN = D / 8;
    constexpr int NPB = 256 / TPN;
    int t = threadIdx.x;
    int node = blockIdx.x * NPB + t / TPN;
    if (node >= N) return;
    int c = (t % TPN) * 8;

    int beg = rowptr[node];
    int end = beg + cnt[node];
    float acc[8] = {0.f, 0.f, 0.f, 0.f, 0.f, 0.f, 0.f, 0.f};
    int e = beg;
    for (; e + 3 < end; e += 4) {
        int s0 = srcIdx[e], s1 = srcIdx[e + 1], s2 = srcIdx[e + 2], s3 = srcIdx[e + 3];
        u16x8 v0 = *(const u16x8*)&h[(size_t)s0 * D + c];
        u16x8 v1 = *(const u16x8*)&h[(size_t)s1 * D + c];
        u16x8 v2 = *(const u16x8*)&h[(size_t)s2 * D + c];
        u16x8 v3 = *(const u16x8*)&h[(size_t)s3 * D + c];
#pragma unroll
        for (int j = 0; j < 8; j++)
            acc[j] += (bf2f(v0[j]) + bf2f(v1[j])) + (bf2f(v2[j]) + bf2f(v3[j]));
    }
    for (; e < end; e++) {
        int s0 = srcIdx[e];
        u16x8 v0 = *(const u16x8*)&h[(size_t)s0 * D + c];
#pragma unroll
        for (int j = 0; j < 8; j++) acc[j] += bf2f(v0[j]);
    }
    float ndv = nd[node];
#pragma unroll
    for (int j = 0; j < 8; j++) acc[j] = acc[j] * ndv + b3[c + j];
    float4* mp = (float4*)&m[(size_t)node * D + c];
    mp[0] = make_float4(acc[0], acc[1], acc[2], acc[3]);
    mp[1] = make_float4(acc[4], acc[5], acc[6], acc[7]);
}

extern "C" void kernel_launch(void* const* d_in, const int* in_sizes, int n_in,
                              void* d_out, int out_size, void* d_ws, size_t ws_size,
                              hipStream_t stream) {
    const float* x  = (const float*)d_in[0];
    const int*   src = (const int*)d_in[1];
    const int*   dst = (const int*)d_in[2];
    const float* W1 = (const float*)d_in[3];
    const float* b1 = (const float*)d_in[4];
    const float* W2 = (const float*)d_in[5];
    const float* b2 = (const float*)d_in[6];
    const float* W3 = (const float*)d_in[7];
    const float* b3 = (const float*)d_in[8];
    float* out = (float*)d_out;

    const int N = NN;
    const int E = in_sizes[1];

    char* ws = (char*)d_ws;
    unsigned short* bufA = (unsigned short*)ws;                 // h1 / h3 (aliases tmpD)
    unsigned short* bufB = (unsigned short*)(ws + (size_t)N * 128 * 4); // A' handoff (aliases tmpS)
    unsigned* tmpD = (unsigned*)bufA;                           // consumed by k_build before gemm1 writes bufA
    unsigned* tmpS = (unsigned*)bufB;                           // consumed by k_build before agg_epi writes bufB
    char*  p     = ws + (size_t)N * 128 * 4 * 2;
    float* ns    = (float*)p;              p += (size_t)N * 4;
    float* nd    = (float*)p;              p += (size_t)N * 4;
    int*   degI  = (int*)p;                p += (size_t)N * 4;
    int*   rowp  = (int*)p;                p += (size_t)N * 4;
    int*   srcIdx= (int*)p;                p += (size_t)E * 4;
    unsigned short* W1h = (unsigned short*)p; p += 128 * 128 * 2;
    unsigned short* W1l = (unsigned short*)p; p += 128 * 128 * 2;
    unsigned short* W2h = (unsigned short*)p; p += 128 * 128 * 2;
    unsigned short* W2l = (unsigned short*)p; p += 128 * 128 * 2;
    unsigned short* W3h = (unsigned short*)p; p += 64 * 128 * 2;
    unsigned short* W3l = (unsigned short*)p; p += 64 * 128 * 2;
    int* bcntS = (int*)p;                  p += 256 * 4;
    int* bcntD = (int*)p;                  p += 256 * 4;
    int* bbaseS= (int*)p;                  p += 256 * 4;
    int* bbaseD= (int*)p;                  p += 256 * 4;
    int* gcurS = (int*)p;                  p += 256 * 4;
    int* gcurD = (int*)p;                  p += 256 * 4;
    int* partS = (int*)p;                  p += (size_t)HB * 256 * 4;
    int* partD = (int*)p;                  p += (size_t)HB * 256 * 4;
    unsigned short* bufC = (unsigned short*)p;                  // h2 (N*128 bf16)

    // W prep (one launch, independent)
    k_prepW_all<<<160, 256, 0, stream>>>(W1, W2, W3, W1h, W1l, W2h, W2l, W3h, W3l);

    // bucketed degree/CSR pipeline (no global atomics in histogram, no memset)
    k_bhist2p<<<HB, 256, 0, stream>>>(src, dst, partS, partD, E);
    k_bscan2<<<1, 256, 0, stream>>>(partS, partD, bcntS, bcntD, bbaseS, gcurS, bbaseD, gcurD);
    k_bscatter3<<<(E + CH - 1) / CH, 256, 0, stream>>>(src, dst, gcurD, gcurS, tmpD, tmpS, E);
    k_build<<<2 * NB, 256, 0, stream>>>(bbaseD, bcntD, tmpD, bbaseS, bcntS, tmpS,
                                        degI, nd, ns, rowp, srcIdx, N);

    const int gemm_grid = (N + 63) / 64;
    const int agg16     = (N + 15) / 16;
    const int agg64     = (N + 31) / 32;

    // ---- layer 1: h1 = (x*ns) @ W1 -> bufA ----
    k_gemm_mfma<128><<<gemm_grid, 256, 0, stream>>>(x, W1h, W1l, ns, bufA, N);

    // ---- layer 2: A2 = epi(Agg(h1)) -> bufB ; h2 = A2 @ W2 -> bufC ----
    k_agg_epi<<<agg16, 256, 0, stream>>>(rowp, degI, srcIdx, bufA, nd, ns, b1, bufB, N);
    k_gemm_bf<128><<<gemm_grid, 256, 0, stream>>>(bufB, W2h, W2l, bufC, N);

    // ---- layer 3: A3 = epi(Agg(h2)) -> bufB ; h3 = A3 @ W3 -> bufA ----
    k_agg_epi<<<agg16, 256, 0, stream>>>(rowp, degI, srcIdx, bufC, nd, ns, b2, bufB, N);
    k_gemm_bf<64><<<gemm_grid, 256, 0, stream>>>(bufB, W3h, W3l, bufA, N);

    // ---- final: out = Agg(h3)*nd + b3 ----
    k_agg_final<64><<<agg64, 256, 0, stream>>>(rowp, degI, srcIdx, bufA, nd, b3, out, N);
}

// Round 14
// 257.104 us; speedup vs baseline: 1.2964x; 1.1070x over previous
//
#include <hip/hip_runtime.h>

#define NN 100000
#define NB 196            // ceil(NN / 512) buckets of 512 nodes
#define CH 4096           // edges per block in scatter
#define BSTRIDE 9216      // fixed per-bucket stride (mean 8192 + 11 sigma)

typedef short short8 __attribute__((ext_vector_type(8)));
typedef unsigned short u16x8 __attribute__((ext_vector_type(8)));
typedef float f32x4 __attribute__((ext_vector_type(4)));

__device__ inline unsigned short f2bf(float x) {
    unsigned u = __float_as_uint(x);
    unsigned r = (u + 0x7FFF + ((u >> 16) & 1)) >> 16;
    return (unsigned short)r;
}
__device__ inline float bf2f(unsigned short h) {
    return __uint_as_float(((unsigned)h) << 16);
}

// ---------------- scatter (fixed-stride buckets) + W prep, one launch ----------------
__global__ __launch_bounds__(256) void k_scatter_prep(
    const int* __restrict__ src, const int* __restrict__ dst,
    int* __restrict__ gcurD, int* __restrict__ gcurS,
    unsigned* __restrict__ tmpD, unsigned* __restrict__ tmpS, int E, int nEdgeBlk,
    const float* __restrict__ W1, const float* __restrict__ W2, const float* __restrict__ W3,
    unsigned short* __restrict__ W1h, unsigned short* __restrict__ W1l,
    unsigned short* __restrict__ W2h, unsigned short* __restrict__ W2l,
    unsigned short* __restrict__ W3h, unsigned short* __restrict__ W3l)
{
    __shared__ int cntD[NB], cntS[NB];
    __shared__ int runD[NB], runS[NB];
    int t = threadIdx.x;

    if (blockIdx.x >= nEdgeBlk) {
        // ---- W prep path ----
        int b = blockIdx.x - nEdgeBlk;
        const float* W; unsigned short *Wh, *Wl; int DOUT, idx;
        if (b < 64)       { W = W1; Wh = W1h; Wl = W1l; DOUT = 128; idx = b * 256 + t; }
        else if (b < 128) { W = W2; Wh = W2h; Wl = W2l; DOUT = 128; idx = (b - 64) * 256 + t; }
        else              { W = W3; Wh = W3h; Wl = W3l; DOUT = 64;  idx = (b - 128) * 256 + t; }
        if (idx >= 128 * DOUT) return;
        int c = idx % DOUT;
        int k = idx / DOUT;
        float w = W[idx];
        unsigned short hi = f2bf(w);
        unsigned short lo = f2bf(w - bf2f(hi));
        int boff = c * 256 + ((2 * k) ^ ((c & 7) << 4));
        *(unsigned short*)((char*)Wh + boff) = hi;
        *(unsigned short*)((char*)Wl + boff) = lo;
        return;
    }

    // ---- counting-claim scatter path ----
    if (t < NB) { cntD[t] = 0; cntS[t] = 0; }
    __syncthreads();

    const int e0 = blockIdx.x * CH;
    int sv[16], dv[16];
    int offD[16], offS[16];
#pragma unroll
    for (int i = 0; i < 16; i++) {
        int e = e0 + i * 256 + t;
        if (e < E) { sv[i] = src[e]; dv[i] = dst[e]; }
    }
#pragma unroll
    for (int i = 0; i < 16; i++) {
        int e = e0 + i * 256 + t;
        if (e < E) {
            offD[i] = atomicAdd(&cntD[dv[i] >> 9], 1);
            offS[i] = atomicAdd(&cntS[sv[i] >> 9], 1);
        }
    }
    __syncthreads();
    if (t < NB) {
        int c = cntD[t];
        if (c) runD[t] = t * BSTRIDE + atomicAdd(&gcurD[t], c);
        c = cntS[t];
        if (c) runS[t] = t * BSTRIDE + atomicAdd(&gcurS[t], c);
    }
    __syncthreads();
#pragma unroll
    for (int i = 0; i < 16; i++) {
        int e = e0 + i * 256 + t;
        if (e < E) {
            int bD = dv[i] >> 9;
            tmpD[runD[bD] + offD[i]] = (unsigned)sv[i] | ((unsigned)(dv[i] & 511) << 17);
            int bS = sv[i] >> 9;
            tmpS[runS[bS] + offS[i]] = (unsigned)(sv[i] & 511);
        }
    }
}

// ---------------- merged build: blocks [0,NB) = dst CSR ; [NB,2NB) = src count -> ns ----------------
__global__ __launch_bounds__(256) void k_build(
    const int* __restrict__ gcurD, const unsigned* __restrict__ tmpD,
    const int* __restrict__ gcurS, const unsigned* __restrict__ tmpS,
    int* __restrict__ degI, float* __restrict__ nd, float* __restrict__ ns,
    int* __restrict__ rowptr, int* __restrict__ srcIdx, int N)
{
    __shared__ int cnt[512];
    __shared__ int sblk[256];
    __shared__ int lcur[512];
    int t = threadIdx.x;

    if (blockIdx.x >= NB) {
        // ---- src-bucket count -> ns ----
        int b = blockIdx.x - NB;
        cnt[t] = 0; cnt[t + 256] = 0;
        __syncthreads();
        int beg = b * BSTRIDE, end = beg + gcurS[b];
        for (int e = beg + t; e < end; e += 256)
            atomicAdd(&cnt[tmpS[e]], 1);
        __syncthreads();
        int nb = b << 9;
        for (int i = t; i < 512; i += 256) {
            int n = nb + i;
            if (n < N) ns[n] = rsqrtf(fmaxf((float)cnt[i], 1.0f));
        }
        return;
    }

    // ---- dst-bucket: degI + nd + rowptr (strided base) + CSR fill ----
    int b = blockIdx.x;
    cnt[t] = 0; cnt[t + 256] = 0;
    __syncthreads();
    int beg = b * BSTRIDE, end = beg + gcurD[b];
    for (int e = beg + t; e < end; e += 256)
        atomicAdd(&cnt[tmpD[e] >> 17], 1);
    __syncthreads();
    int v0 = cnt[2 * t], v1 = cnt[2 * t + 1];
    sblk[t] = v0 + v1;
    __syncthreads();
#pragma unroll
    for (int off = 1; off < 256; off <<= 1) {
        int x = (t >= off) ? sblk[t - off] : 0;
        __syncthreads(); sblk[t] += x; __syncthreads();
    }
    int e0 = beg + sblk[t] - v0 - v1;
    int e1_ = e0 + v0;
    int nb = b << 9;
    int n0 = nb + 2 * t, n1 = n0 + 1;
    if (n0 < N) { rowptr[n0] = e0;  degI[n0] = v0; nd[n0] = rsqrtf(fmaxf((float)v0, 1.f)); }
    if (n1 < N) { rowptr[n1] = e1_; degI[n1] = v1; nd[n1] = rsqrtf(fmaxf((float)v1, 1.f)); }
    lcur[2 * t] = e0; lcur[2 * t + 1] = e1_;
    __syncthreads();
    for (int e = beg + t; e < end; e += 256) {
        unsigned v = tmpD[e];
        int pos = atomicAdd(&lcur[v >> 17], 1);
        srcIdx[pos] = (int)(v & 0x1FFFFu);
    }
}

// ---------------- MFMA GEMM layer 1: out[n][:] = (x[n][:]*ns[n]) @ W  (f32 in, bf16 out) ----------------
template<int DOUT>
__global__ __launch_bounds__(256) void k_gemm_mfma(
    const float* __restrict__ in,
    const unsigned short* __restrict__ Wth, const unsigned short* __restrict__ Wtl,
    const float* __restrict__ ns,
    unsigned short* __restrict__ out, int N)
{
    constexpr int NT = DOUT / 16;
    __shared__ __align__(16) unsigned short Wh[DOUT * 128];
    __shared__ __align__(16) unsigned short Wl[DOUT * 128];

    const int t = threadIdx.x;
    const int w = t >> 6, l = t & 63;

#pragma unroll
    for (int i = 0; i < DOUT * 256 / 4096; i++) {
        int off = i * 4096 + t * 16;
        *(float4*)((char*)Wh + off) = *(const float4*)((const char*)Wth + off);
        *(float4*)((char*)Wl + off) = *(const float4*)((const char*)Wtl + off);
    }

    const int rl   = l & 15;
    const int kgrp = l >> 4;
    const int row  = blockIdx.x * 64 + w * 16 + rl;
    const int rowc = row < N ? row : N - 1;
    const float* arow = in + (size_t)rowc * 128;

    float av[4][8];
#pragma unroll
    for (int ks = 0; ks < 4; ks++) {
        int kb = ks * 32 + kgrp * 8;
        float4 v0 = *(const float4*)(arow + kb);
        float4 v1 = *(const float4*)(arow + kb + 4);
        av[ks][0] = v0.x; av[ks][1] = v0.y; av[ks][2] = v0.z; av[ks][3] = v0.w;
        av[ks][4] = v1.x; av[ks][5] = v1.y; av[ks][6] = v1.z; av[ks][7] = v1.w;
    }
    float nsv = ns[rowc];
    short8 Ah[4], Al[4];
#pragma unroll
    for (int ks = 0; ks < 4; ks++)
#pragma unroll
        for (int j = 0; j < 8; j++) {
            float v = av[ks][j] * nsv;
            unsigned short hi = f2bf(v);
            Ah[ks][j] = (short)hi;
            Al[ks][j] = (short)f2bf(v - bf2f(hi));
        }

    __syncthreads();

    f32x4 acc[NT];
#pragma unroll
    for (int tt = 0; tt < NT; tt++) acc[tt] = (f32x4){0.f, 0.f, 0.f, 0.f};

#pragma unroll
    for (int ks = 0; ks < 4; ks++) {
        int kbyte = ks * 64 + kgrp * 16;
#pragma unroll
        for (int tt = 0; tt < NT; tt++) {
            int c = tt * 16 + rl;
            int boff = c * 256 + (kbyte ^ ((c & 7) << 4));
            short8 Bh = *(short8*)((char*)Wh + boff);
            short8 Bl = *(short8*)((char*)Wl + boff);
            acc[tt] = __builtin_amdgcn_mfma_f32_16x16x32_bf16(Ah[ks], Bh, acc[tt], 0, 0, 0);
            acc[tt] = __builtin_amdgcn_mfma_f32_16x16x32_bf16(Al[ks], Bh, acc[tt], 0, 0, 0);
            acc[tt] = __builtin_amdgcn_mfma_f32_16x16x32_bf16(Ah[ks], Bl, acc[tt], 0, 0, 0);
        }
    }

    const int orow = blockIdx.x * 64 + w * 16 + kgrp * 4;
#pragma unroll
    for (int r = 0; r < 4; r++) {
        if (orow + r < N) {
#pragma unroll
            for (int tt = 0; tt < NT; tt++)
                out[(size_t)(orow + r) * DOUT + tt * 16 + rl] = f2bf(acc[tt][r]);
        }
    }
}

// ---------------- gather + epilogue -> bf16 A (barrier-free, 4-deep unroll) ----------------
__global__ __launch_bounds__(256) void k_agg_epi(
    const int* __restrict__ rowptr, const int* __restrict__ cnt,
    const int* __restrict__ srcIdx, const unsigned short* __restrict__ h,
    const float* __restrict__ nd, const float* __restrict__ ns,
    const float* __restrict__ bias,
    unsigned short* __restrict__ out, int N)
{
    int t = threadIdx.x;
    int node = blockIdx.x * 16 + (t >> 4);
    if (node >= N) return;
    int c = (t & 15) * 8;

    int beg = rowptr[node];
    int end = beg + cnt[node];
    float acc[8] = {0.f, 0.f, 0.f, 0.f, 0.f, 0.f, 0.f, 0.f};
    int e = beg;
    for (; e + 3 < end; e += 4) {
        int s0 = srcIdx[e], s1 = srcIdx[e + 1], s2 = srcIdx[e + 2], s3 = srcIdx[e + 3];
        u16x8 v0 = *(const u16x8*)&h[(size_t)s0 * 128 + c];
        u16x8 v1 = *(const u16x8*)&h[(size_t)s1 * 128 + c];
        u16x8 v2 = *(const u16x8*)&h[(size_t)s2 * 128 + c];
        u16x8 v3 = *(const u16x8*)&h[(size_t)s3 * 128 + c];
#pragma unroll
        for (int j = 0; j < 8; j++)
            acc[j] += (bf2f(v0[j]) + bf2f(v1[j])) + (bf2f(v2[j]) + bf2f(v3[j]));
    }
    for (; e < end; e++) {
        int s0 = srcIdx[e];
        u16x8 v0 = *(const u16x8*)&h[(size_t)s0 * 128 + c];
#pragma unroll
        for (int j = 0; j < 8; j++) acc[j] += bf2f(v0[j]);
    }
    float ndv = nd[node], nsv = ns[node];
    float4 b0 = *(const float4*)(bias + c);
    float4 b1 = *(const float4*)(bias + c + 4);
    float bb[8] = {b0.x, b0.y, b0.z, b0.w, b1.x, b1.y, b1.z, b1.w};
    u16x8 o;
#pragma unroll
    for (int j = 0; j < 8; j++)
        o[j] = f2bf(fmaxf(acc[j] * ndv + bb[j], 0.f) * nsv);
    *(u16x8*)&out[(size_t)node * 128 + c] = o;
}

// ---------------- bf16-A MFMA GEMM: out = A @ W (A bf16 N×128, W hi/lo) ----------------
template<int DOUT>
__global__ __launch_bounds__(256) void k_gemm_bf(
    const unsigned short* __restrict__ in,
    const unsigned short* __restrict__ Wth, const unsigned short* __restrict__ Wtl,
    unsigned short* __restrict__ out, int N)
{
    constexpr int NT = DOUT / 16;
    __shared__ __align__(16) unsigned short Wh[DOUT * 128];
    __shared__ __align__(16) unsigned short Wl[DOUT * 128];

    const int t = threadIdx.x;
    const int w = t >> 6, l = t & 63;

#pragma unroll
    for (int i = 0; i < DOUT * 256 / 4096; i++) {
        int off = i * 4096 + t * 16;
        *(float4*)((char*)Wh + off) = *(const float4*)((const char*)Wth + off);
        *(float4*)((char*)Wl + off) = *(const float4*)((const char*)Wtl + off);
    }

    const int rl   = l & 15;
    const int kgrp = l >> 4;
    const int row  = blockIdx.x * 64 + w * 16 + rl;
    const int rowc = row < N ? row : N - 1;
    const unsigned short* arow = in + (size_t)rowc * 128;

    short8 Ah[4];
#pragma unroll
    for (int ks = 0; ks < 4; ks++)
        Ah[ks] = *(const short8*)(arow + ks * 32 + kgrp * 8);

    __syncthreads();

    f32x4 acc[NT];
#pragma unroll
    for (int tt = 0; tt < NT; tt++) acc[tt] = (f32x4){0.f, 0.f, 0.f, 0.f};

#pragma unroll
    for (int ks = 0; ks < 4; ks++) {
        int kbyte = ks * 64 + kgrp * 16;
#pragma unroll
        for (int tt = 0; tt < NT; tt++) {
            int c = tt * 16 + rl;
            int boff = c * 256 + (kbyte ^ ((c & 7) << 4));
            short8 Bh = *(short8*)((char*)Wh + boff);
            short8 Bl = *(short8*)((char*)Wl + boff);
            acc[tt] = __builtin_amdgcn_mfma_f32_16x16x32_bf16(Ah[ks], Bh, acc[tt], 0, 0, 0);
            acc[tt] = __builtin_amdgcn_mfma_f32_16x16x32_bf16(Ah[ks], Bl, acc[tt], 0, 0, 0);
        }
    }

    const int orow = blockIdx.x * 64 + w * 16 + kgrp * 4;
#pragma unroll
    for (int r = 0; r < 4; r++) {
        if (orow + r < N) {
#pragma unroll
            for (int tt = 0; tt < NT; tt++)
                out[(size_t)(orow + r) * DOUT + tt * 16 + rl] = f2bf(acc[tt][r]);
        }
    }
}

// ---------------- final aggregation (bf16 gather, f32 accumulate, epilogue, 4-deep) ----------------
template<int D>
__global__ __launch_bounds__(256) void k_agg_final(
    const int* __restrict__ rowptr, const int* __restrict__ cnt,
    const int* __restrict__ srcIdx, const unsigned short* __restrict__ h,
    const float* __restrict__ nd, const float* __restrict__ b3,
    float* __restrict__ m, int N)
{
    constexpr int TPN = D / 8;
    constexpr int NPB = 256 / TPN;
    int t = threadIdx.x;
    int node = blockIdx.x * NPB + t / TPN;
    if (node >= N) return;
    int c = (t % TPN) * 8;

    int beg = rowptr[node];
    int end = beg + cnt[node];
    float acc[8] = {0.f, 0.f, 0.f, 0.f, 0.f, 0.f, 0.f, 0.f};
    int e = beg;
    for (; e + 3 < end; e += 4) {
        int s0 = srcIdx[e], s1 = srcIdx[e + 1], s2 = srcIdx[e + 2], s3 = srcIdx[e + 3];
        u16x8 v0 = *(const u16x8*)&h[(size_t)s0 * D + c];
        u16x8 v1 = *(const u16x8*)&h[(size_t)s1 * D + c];
        u16x8 v2 = *(const u16x8*)&h[(size_t)s2 * D + c];
        u16x8 v3 = *(const u16x8*)&h[(size_t)s3 * D + c];
#pragma unroll
        for (int j = 0; j < 8; j++)
            acc[j] += (bf2f(v0[j]) + bf2f(v1[j])) + (bf2f(v2[j]) + bf2f(v3[j]));
    }
    for (; e < end; e++) {
        int s0 = srcIdx[e];
        u16x8 v0 = *(const u16x8*)&h[(size_t)s0 * D + c];
#pragma unroll
        for (int j = 0; j < 8; j++) acc[j] += bf2f(v0[j]);
    }
    float ndv = nd[node];
#pragma unroll
    for (int j = 0; j < 8; j++) acc[j] = acc[j] * ndv + b3[c + j];
    float4* mp = (float4*)&m[(size_t)node * D + c];
    mp[0] = make_float4(acc[0], acc[1], acc[2], acc[3]);
    mp[1] = make_float4(acc[4], acc[5], acc[6], acc[7]);
}

extern "C" void kernel_launch(void* const* d_in, const int* in_sizes, int n_in,
                              void* d_out, int out_size, void* d_ws, size_t ws_size,
                              hipStream_t stream) {
    const float* x  = (const float*)d_in[0];
    const int*   src = (const int*)d_in[1];
    const int*   dst = (const int*)d_in[2];
    const float* W1 = (const float*)d_in[3];
    const float* b1 = (const float*)d_in[4];
    const float* W2 = (const float*)d_in[5];
    const float* b2 = (const float*)d_in[6];
    const float* W3 = (const float*)d_in[7];
    const float* b3 = (const float*)d_in[8];
    float* out = (float*)d_out;

    const int N = NN;
    const int E = in_sizes[1];
    const int nEdgeBlk = (E + CH - 1) / CH;

    char* ws = (char*)d_ws;
    unsigned short* bufA = (unsigned short*)ws;                 // h1 / h3 (aliases tmpD)
    unsigned short* bufB = (unsigned short*)(ws + (size_t)N * 128 * 4); // A' handoff (aliases tmpS)
    unsigned* tmpD = (unsigned*)bufA;                           // NB*BSTRIDE u32; consumed by k_build before gemm1 writes bufA
    unsigned* tmpS = (unsigned*)bufB;                           // NB*BSTRIDE u32; consumed by k_build before agg_epi writes bufB
    char*  p     = ws + (size_t)N * 128 * 4 * 2;
    float* ns    = (float*)p;              p += (size_t)N * 4;
    float* nd    = (float*)p;              p += (size_t)N * 4;
    int*   degI  = (int*)p;                p += (size_t)N * 4;
    int*   rowp  = (int*)p;                p += (size_t)N * 4;
    int*   srcIdx= (int*)p;                p += (size_t)NB * BSTRIDE * 4;
    unsigned short* W1h = (unsigned short*)p; p += 128 * 128 * 2;
    unsigned short* W1l = (unsigned short*)p; p += 128 * 128 * 2;
    unsigned short* W2h = (unsigned short*)p; p += 128 * 128 * 2;
    unsigned short* W2l = (unsigned short*)p; p += 128 * 128 * 2;
    unsigned short* W3h = (unsigned short*)p; p += 64 * 128 * 2;
    unsigned short* W3l = (unsigned short*)p; p += 64 * 128 * 2;
    int* gcurD = (int*)p;                  p += 256 * 4;
    int* gcurS = (int*)p;                  p += 256 * 4;   // contiguous with gcurD for one memset
    unsigned short* bufC = (unsigned short*)p;                  // h2 (N*128 bf16)

    // zero bucket cursors (2 KB), then scatter + W prep in one launch
    hipMemsetAsync(gcurD, 0, 2 * 256 * 4, stream);
    k_scatter_prep<<<nEdgeBlk + 160, 256, 0, stream>>>(src, dst, gcurD, gcurS,
        tmpD, tmpS, E, nEdgeBlk, W1, W2, W3, W1h, W1l, W2h, W2l, W3h, W3l);
    k_build<<<2 * NB, 256, 0, stream>>>(gcurD, tmpD, gcurS, tmpS,
                                        degI, nd, ns, rowp, srcIdx, N);

    const int gemm_grid = (N + 63) / 64;
    const int agg16     = (N + 15) / 16;
    const int agg64     = (N + 31) / 32;

    // ---- layer 1: h1 = (x*ns) @ W1 -> bufA ----
    k_gemm_mfma<128><<<gemm_grid, 256, 0, stream>>>(x, W1h, W1l, ns, bufA, N);

    // ---- layer 2: A2 = epi(Agg(h1)) -> bufB ; h2 = A2 @ W2 -> bufC ----
    k_agg_epi<<<agg16, 256, 0, stream>>>(rowp, degI, srcIdx, bufA, nd, ns, b1, bufB, N);
    k_gemm_bf<128><<<gemm_grid, 256, 0, stream>>>(bufB, W2h, W2l, bufC, N);

    // ---- layer 3: A3 = epi(Agg(h2)) -> bufB ; h3 = A3 @ W3 -> bufA ----
    k_agg_epi<<<agg16, 256, 0, stream>>>(rowp, degI, srcIdx, bufC, nd, ns, b2, bufB, N);
    k_gemm_bf<64><<<gemm_grid, 256, 0, stream>>>(bufB, W3h, W3l, bufA, N);

    // ---- final: out = Agg(h3)*nd + b3 ----
    k_agg_final<64><<<agg64, 256, 0, stream>>>(rowp, degI, srcIdx, bufA, nd, b3, out, N);
}